// Round 4
// baseline (218.437 us; speedup 1.0000x reference)
//
#include <hip/hip_runtime.h>

typedef __attribute__((ext_vector_type(8))) short short8;
typedef __attribute__((ext_vector_type(4))) float floatx4;

#define IN_C 128
#define OUT_C 256
#define NB 32
#define HW 56
#define S_PER_N (HW * HW)          // 3136
#define M_TOTAL (NB * S_PER_N)     // 100352
#define PH 58                      // padded height
#define PW 66                      // padded width
#define XN_ELEMS (NB * PH * PW * IN_C)   // 15,679,488
#define WT_ELEMS (9 * OUT_C * IN_C)      // 294,912

__device__ __forceinline__ unsigned short f2bf(float f) {
    unsigned int u = __builtin_bit_cast(unsigned int, f);
    u = (u + 0x7FFFu + ((u >> 16) & 1u)) >> 16;   // RNE
    return (unsigned short)u;
}

// Direct global->LDS DMA, 16B per lane. LDS dest is wave-uniform base + lane*16.
__device__ __forceinline__ void gld_lds16(const unsigned short* g, unsigned short* l) {
    __builtin_amdgcn_global_load_lds(
        (const __attribute__((address_space(1))) unsigned int*)g,
        (__attribute__((address_space(3))) unsigned int*)l, 16, 0, 0);
}

// x (N,C,56,56) fp32  ->  xn (N,58,66,C) bf16 with zero halo baked in.
__global__ void xform_x(const float* __restrict__ x, unsigned short* __restrict__ xn) {
    const int ihp = blockIdx.x;          // 0..57
    const int n   = blockIdx.y;          // 0..31
    const int tid = threadIdx.x;         // 256 threads
    unsigned int* __restrict__ row32 =
        (unsigned int*)(xn + (size_t)(n * PH + ihp) * PW * IN_C);
    const int WORDS = PW * IN_C / 2;     // 4224 uint32 per row

    if (ihp == 0 || ihp == PH - 1) {
        for (int i = tid; i < WORDS; i += 256) row32[i] = 0u;
        return;
    }
    const int ih = ihp - 1;
    __shared__ unsigned short lds2[HW][IN_C];   // [iw][ic] bf16, 14336 B
    const float* __restrict__ xrow = x + (size_t)n * IN_C * S_PER_N + (size_t)ih * HW;
    for (int i = tid; i < IN_C * 14; i += 256) {   // float4 per (ic, iw4)
        int ic = i / 14, iw4 = (i % 14) * 4;
        float4 v = *(const float4*)(xrow + (size_t)ic * S_PER_N + iw4);
        lds2[iw4 + 0][ic] = f2bf(v.x);
        lds2[iw4 + 1][ic] = f2bf(v.y);
        lds2[iw4 + 2][ic] = f2bf(v.z);
        lds2[iw4 + 3][ic] = f2bf(v.w);
    }
    __syncthreads();
    for (int wi = tid; wi < WORDS; wi += 256) {
        int pix = wi >> 6;               // 0..65
        int icw = wi & 63;               // ic pair index
        unsigned int val = 0u;
        if (pix >= 1 && pix <= HW)
            val = *(const unsigned int*)&lds2[pix - 1][icw * 2];
        row32[wi] = val;
    }
}

// w (256,128,3,3) fp32 -> wt[khw][oc][ic] bf16
__global__ void xform_w(const float* __restrict__ w, unsigned short* __restrict__ wt) {
    const int idx = blockIdx.x * 256 + threadIdx.x;   // grid exact
    const int ic  = idx & 127;
    const int oc  = (idx >> 7) & 255;
    const int khw = idx >> 15;
    wt[idx] = f2bf(w[(oc * IN_C + ic) * 9 + khw]);
}

// Implicit GEMM. BK=32, DOUBLE-BUFFERED LDS (one barrier per tile; DMA for
// tile t+1 issued right after the barrier so it has a full compute phase in
// flight before the next barrier's vmcnt drain). XOR-swizzled LDS layout:
// staging lane (row,ci) fetches global ic-block ci^(row&3); fragment reads
// address block quad^(l15&3) -> conflict-free b128 (8-cycle floor).
// Block 128 oc x 128 s, 4 waves, wave 64x64 (4x4 of 16x16x32 bf16 MFMA).
__global__ void __launch_bounds__(256, 3)
conv_mfma(const unsigned short* __restrict__ xn,
          const unsigned short* __restrict__ wt,
          float* __restrict__ out) {
    const int tid  = threadIdx.x;
    const int lane = tid & 63;
    const int wv   = tid >> 6;        // 0..3
    const int l15  = lane & 15;
    const int quad = lane >> 4;       // 0..3

    const int bx      = blockIdx.x;
    const int tile_oc = bx & 1;       // 2 oc tiles of 128
    const int tile_m  = bx >> 1;      // 784 spatial tiles of 128

    const int s_blk  = tile_m * 128;
    const int oc_blk = tile_oc * 128;
    const int s0  = s_blk + (wv & 1) * 64;    // wave spatial base
    const int oc0 = oc_blk + (wv >> 1) * 64;  // wave oc base

    __shared__ unsigned short A_lds[2 * 128 * 32];   // dbuf, 2 x 8 KB
    __shared__ unsigned short B_lds[2 * 128 * 32];   // dbuf, 2 x 8 KB

    // ---- staging: thread -> (row = q*64 + tid>>2, swizzled ic-block) ----
    const int srow = tid >> 2;                    // 0..63
    const int ci   = tid & 3;                     // 0..3
    const int sic  = (ci ^ (srow & 3)) * 8;       // swizzled source offset

    const unsigned short* a_g[2];
    const unsigned short* b_g[2];
#pragma unroll
    for (int q = 0; q < 2; ++q) {
        int row = q * 64 + srow;
        a_g[q] = wt + (size_t)(oc_blk + row) * IN_C + sic;
        int sg = s_blk + row;
        int n  = sg / S_PER_N;
        int r  = sg % S_PER_N;
        int oh = r / HW, ow = r % HW;
        b_g[q] = xn + (size_t)((n * PH + oh) * PW + ow) * IN_C + sic;
    }
    // LDS dest (elems): buf*4096 + q*2048 + tid*8  (16B per lane)
    unsigned short* a_l = A_lds + tid * 8;
    unsigned short* b_l = B_lds + tid * 8;

    // ---- fragment read offsets (elems), row stride 32, swizzled k-block ----
    int arow[4], brow[4];
#pragma unroll
    for (int i = 0; i < 4; ++i)
        arow[i] = ((wv >> 1) * 64 + i * 16 + l15) * 32;
#pragma unroll
    for (int j = 0; j < 4; ++j)
        brow[j] = ((wv & 1) * 64 + j * 16 + l15) * 32;
    const int koff = (quad ^ (l15 & 3)) * 8;      // swizzled 16B block in row

    floatx4 acc[4][4];
#pragma unroll
    for (int i = 0; i < 4; ++i)
#pragma unroll
        for (int j = 0; j < 4; ++j) acc[i][j] = (floatx4){0.f, 0.f, 0.f, 0.f};

    // tile t (0..35): khw = t>>2, k-chunk = (t&3)*32
    auto issue = [&](int t, int buf) {
        int khw = t >> 2;
        int sub = (t & 3) * 32;
        int xo = ((khw / 3) * PW + (khw % 3)) * IN_C + sub;
        int wo = khw * OUT_C * IN_C + sub;
        int lb = buf * 4096;
#pragma unroll
        for (int q = 0; q < 2; ++q) {
            gld_lds16(a_g[q] + wo, a_l + lb + q * 2048);
            gld_lds16(b_g[q] + xo, b_l + lb + q * 2048);
        }
    };

    issue(0, 0);
#pragma unroll
    for (int t = 0; t < 36; ++t) {
        __syncthreads();              // DMA(t) drained; buf[(t+1)&1] consumed
        if (t < 35) issue(t + 1, (t + 1) & 1);
        const unsigned short* Ab = A_lds + (t & 1) * 4096;
        const unsigned short* Bb = B_lds + (t & 1) * 4096;
        short8 a[4], b[4];
#pragma unroll
        for (int i = 0; i < 4; ++i) a[i] = *(const short8*)(Ab + arow[i] + koff);
#pragma unroll
        for (int j = 0; j < 4; ++j) b[j] = *(const short8*)(Bb + brow[j] + koff);
#pragma unroll
        for (int i = 0; i < 4; ++i)
#pragma unroll
            for (int j = 0; j < 4; ++j)
                acc[i][j] = __builtin_amdgcn_mfma_f32_16x16x32_bf16(
                    a[i], b[j], acc[i][j], 0, 0, 0);
    }

    // Epilogue: C/D layout col=lane&15 (s), row=quad*4+reg (oc).
#pragma unroll
    for (int j = 0; j < 4; ++j) {
        int s_glob = s0 + j * 16 + l15;
        int n = s_glob / S_PER_N;
        int s = s_glob % S_PER_N;
        float* obase = out + (size_t)n * OUT_C * S_PER_N + s;
#pragma unroll
        for (int i = 0; i < 4; ++i) {
            int oc = oc0 + i * 16 + quad * 4;
#pragma unroll
            for (int r = 0; r < 4; ++r)
                obase[(size_t)(oc + r) * S_PER_N] = acc[i][j][r];
        }
    }
}

extern "C" void kernel_launch(void* const* d_in, const int* in_sizes, int n_in,
                              void* d_out, int out_size, void* d_ws, size_t ws_size,
                              hipStream_t stream) {
    const float* x = (const float*)d_in[0];
    const float* w = (const float*)d_in[1];
    float* out = (float*)d_out;

    unsigned short* xn = (unsigned short*)d_ws;      // 31,358,976 B
    unsigned short* wt = xn + XN_ELEMS;              // 589,824 B

    dim3 gx(PH, NB);
    xform_x<<<gx, 256, 0, stream>>>(x, xn);
    xform_w<<<WT_ELEMS / 256, 256, 0, stream>>>(w, wt);
    conv_mfma<<<(M_TOTAL / 128) * 2, 256, 0, stream>>>(xn, wt, out);
}